// Round 15
// baseline (438.761 us; speedup 1.0000x reference)
//
#include <hip/hip_runtime.h>

#define NBQ 12544
#define DM  256
#define MM  2048

typedef __attribute__((ext_vector_type(8)))  __bf16 bf16x8;
typedef __attribute__((ext_vector_type(4)))  float  floatx4;

__device__ __forceinline__ ushort f2bf(float x) {
    unsigned u = __float_as_uint(x);
    u += 0x7fffu + ((u >> 16) & 1u);   // RNE
    return (ushort)(u >> 16);
}
__device__ __forceinline__ float bf2f(ushort h) {
    return __uint_as_float(((unsigned)h) << 16);
}

// ---------- projections + inline KF row-stats (r14-proven, unchanged) ----------
__global__ __launch_bounds__(256) void proj_stats(
    const float* __restrict__ x,      const float* __restrict__ ch_mem,
    const float* __restrict__ sp_mem,
    const float* __restrict__ ch_wq,  const float* __restrict__ sp_wq,
    const float* __restrict__ ch_wk,  const float* __restrict__ ch_wv,
    const float* __restrict__ sp_wk,  const float* __restrict__ sp_wv,
    ushort* __restrict__ Qb,  ushort* __restrict__ QFb,
    ushort* __restrict__ Kb,  ushort* __restrict__ KFb,
    ushort* __restrict__ Vtb, ushort* __restrict__ VFtb,
    float* __restrict__ km,   float* __restrict__ kv)
{
    __shared__ ushort As[64][264];
    __shared__ ushort W1s[64][72];
    __shared__ ushort W2s[64][72];
    __shared__ float  sbuf[4][4][8];
    __shared__ float  ssbuf[4][4][8];

    int bid = blockIdx.x;
    const float* A; const float* W1; const float* W2;
    ushort* C1; ushort* C2; int nrows, trans2, dostats;
    if (bid < 196) {
        A = x; W1 = ch_wq; W2 = sp_wq; C1 = Qb; C2 = QFb;
        nrows = NBQ; trans2 = 0; dostats = 0;
    } else if (bid < 228) {
        A = ch_mem; W1 = ch_wk; W2 = ch_wv; C1 = Kb; C2 = Vtb;
        nrows = MM; trans2 = 1; dostats = 0; bid -= 196;
    } else {
        A = sp_mem; W1 = sp_wk; W2 = sp_wv; C1 = KFb; C2 = VFtb;
        nrows = MM; trans2 = 1; dostats = 1; bid -= 228;
    }
    const int r0 = bid * 64;

    const int tid  = threadIdx.x;
    const int wv   = tid >> 6;
    const int lane = tid & 63;
    const int quad = lane >> 4;
    const int l16  = lane & 15;
    const int rw = (wv & 1) * 32;
    const int cw = (wv >> 1) * 32;

    #pragma unroll
    for (int it = 0; it < 8; ++it) {
        int idx = tid + it * 256;
        int r = idx >> 5, c8 = (idx & 31) * 8;
        const float* ap = A + (size_t)(r0 + r) * 256 + c8;
        float4 a0 = *(const float4*)ap;
        float4 a1 = *(const float4*)(ap + 4);
        ushort4 b0, b1;
        b0.x = f2bf(a0.x); b0.y = f2bf(a0.y); b0.z = f2bf(a0.z); b0.w = f2bf(a0.w);
        b1.x = f2bf(a1.x); b1.y = f2bf(a1.y); b1.z = f2bf(a1.z); b1.w = f2bf(a1.w);
        *(ushort4*)&As[r][c8]     = b0;
        *(ushort4*)&As[r][c8 + 4] = b1;
    }

    float s8[8]  = {0.f, 0.f, 0.f, 0.f, 0.f, 0.f, 0.f, 0.f};
    float ss8[8] = {0.f, 0.f, 0.f, 0.f, 0.f, 0.f, 0.f, 0.f};

    for (int c0 = 0; c0 < 256; c0 += 64) {
        floatx4 acc1[2][2], acc2[2][2];
        #pragma unroll
        for (int i = 0; i < 2; ++i)
            #pragma unroll
            for (int j = 0; j < 2; ++j) {
                acc1[i][j] = (floatx4){0.f, 0.f, 0.f, 0.f};
                acc2[i][j] = (floatx4){0.f, 0.f, 0.f, 0.f};
            }

        for (int d0 = 0; d0 < 256; d0 += 64) {
            __syncthreads();
            #pragma unroll
            for (int it = 0; it < 4; ++it) {
                int idx = tid + it * 256;
                int which = idx >> 9;
                int rem = idx & 511;
                int r = rem >> 3, c8 = (rem & 7) * 8;
                const float* wp = (which ? W2 : W1) + (size_t)(c0 + r) * 256 + d0 + c8;
                float4 w0 = *(const float4*)wp;
                float4 w1 = *(const float4*)(wp + 4);
                ushort4 b0, b1;
                b0.x = f2bf(w0.x); b0.y = f2bf(w0.y); b0.z = f2bf(w0.z); b0.w = f2bf(w0.w);
                b1.x = f2bf(w1.x); b1.y = f2bf(w1.y); b1.z = f2bf(w1.z); b1.w = f2bf(w1.w);
                ushort* dst = which ? &W2s[r][c8] : &W1s[r][c8];
                *(ushort4*)dst       = b0;
                *(ushort4*)(dst + 4) = b1;
            }
            __syncthreads();
            #pragma unroll
            for (int kk = 0; kk < 64; kk += 32) {
                bf16x8 aA0 = *(const bf16x8*)&As[rw + l16][d0 + kk + quad * 8];
                bf16x8 aA1 = *(const bf16x8*)&As[rw + 16 + l16][d0 + kk + quad * 8];
                bf16x8 b10 = *(const bf16x8*)&W1s[cw + l16][kk + quad * 8];
                bf16x8 b11 = *(const bf16x8*)&W1s[cw + 16 + l16][kk + quad * 8];
                bf16x8 b20 = *(const bf16x8*)&W2s[cw + l16][kk + quad * 8];
                bf16x8 b21 = *(const bf16x8*)&W2s[cw + 16 + l16][kk + quad * 8];
                acc1[0][0] = __builtin_amdgcn_mfma_f32_16x16x32_bf16(aA0, b10, acc1[0][0], 0, 0, 0);
                acc1[0][1] = __builtin_amdgcn_mfma_f32_16x16x32_bf16(aA0, b11, acc1[0][1], 0, 0, 0);
                acc1[1][0] = __builtin_amdgcn_mfma_f32_16x16x32_bf16(aA1, b10, acc1[1][0], 0, 0, 0);
                acc1[1][1] = __builtin_amdgcn_mfma_f32_16x16x32_bf16(aA1, b11, acc1[1][1], 0, 0, 0);
                acc2[0][0] = __builtin_amdgcn_mfma_f32_16x16x32_bf16(aA0, b20, acc2[0][0], 0, 0, 0);
                acc2[0][1] = __builtin_amdgcn_mfma_f32_16x16x32_bf16(aA0, b21, acc2[0][1], 0, 0, 0);
                acc2[1][0] = __builtin_amdgcn_mfma_f32_16x16x32_bf16(aA1, b20, acc2[1][0], 0, 0, 0);
                acc2[1][1] = __builtin_amdgcn_mfma_f32_16x16x32_bf16(aA1, b21, acc2[1][1], 0, 0, 0);
            }
        }

        if (dostats) {
            #pragma unroll
            for (int ag = 0; ag < 2; ++ag)
                #pragma unroll
                for (int i = 0; i < 4; ++i) {
                    float v0 = acc1[ag][0][i], v1 = acc1[ag][1][i];
                    s8[ag * 4 + i]  += v0 + v1;
                    ss8[ag * 4 + i] += v0 * v0 + v1 * v1;
                }
        }

        #pragma unroll
        for (int ag = 0; ag < 2; ++ag)
            #pragma unroll
            for (int cg = 0; cg < 2; ++cg)
                #pragma unroll
                for (int i = 0; i < 4; ++i)
                    C1[(size_t)(r0 + rw + ag * 16 + quad * 4 + i) * 256
                       + c0 + cw + cg * 16 + l16] = f2bf(acc1[ag][cg][i]);

        if (!trans2) {
            #pragma unroll
            for (int ag = 0; ag < 2; ++ag)
                #pragma unroll
                for (int cg = 0; cg < 2; ++cg)
                    #pragma unroll
                    for (int i = 0; i < 4; ++i)
                        C2[(size_t)(r0 + rw + ag * 16 + quad * 4 + i) * 256
                           + c0 + cw + cg * 16 + l16] = f2bf(acc2[ag][cg][i]);
        } else {
            __syncthreads();
            #pragma unroll
            for (int ag = 0; ag < 2; ++ag)
                #pragma unroll
                for (int cg = 0; cg < 2; ++cg)
                    #pragma unroll
                    for (int i = 0; i < 4; ++i)
                        W2s[cw + cg * 16 + l16][rw + ag * 16 + quad * 4 + i] =
                            f2bf(acc2[ag][cg][i]);
            __syncthreads();
            const int col = tid >> 2;
            const int seg = (tid & 3) * 16;
            #pragma unroll
            for (int j = 0; j < 2; ++j)
                *(uint4*)(C2 + (size_t)(c0 + col) * nrows + r0 + seg + j * 8) =
                    *(const uint4*)&W2s[col][seg + j * 8];
        }
    }

    if (dostats) {
        #pragma unroll
        for (int k = 0; k < 8; ++k) {
            #pragma unroll
            for (int m = 1; m < 16; m <<= 1) {
                s8[k]  += __shfl_xor(s8[k], m, 64);
                ss8[k] += __shfl_xor(ss8[k], m, 64);
            }
        }
        if (l16 == 0) {
            #pragma unroll
            for (int k = 0; k < 8; ++k) {
                sbuf[wv][quad][k]  = s8[k];
                ssbuf[wv][quad][k] = ss8[k];
            }
        }
        __syncthreads();
        if (tid < 64) {
            int rl = tid;
            int wvb  = rl >> 5;
            int qd   = (rl >> 2) & 3;
            int idx8 = ((rl >> 4) & 1) * 4 + (rl & 3);
            float s  = sbuf[wvb][qd][idx8]  + sbuf[2 + wvb][qd][idx8];
            float ss = ssbuf[wvb][qd][idx8] + ssbuf[2 + wvb][qd][idx8];
            float m = s * (1.f / 256.f);
            km[r0 + rl] = m;
            kv[r0 + rl] = (ss - 256.f * m * m) * (1.f / 255.f);
        }
    }
}

// ---------------- fused attention: r13 S^T structure + K/V LDS ALIASING ----------
// K/KF live only during score; Vt/VFt only during PV -> one 40,960 B buffer holds
// K+KF, then is overwritten with Vt+VFt after the score barrier. LDS 74,752 ->
// 40,960 B => 3 blocks/CU (12 waves/CU, 3/SIMD). Full-key lockstep walk preserved
// (no key-split) so L2 reuse stays intact. 4 barriers/tile (was 2).
__global__ __launch_bounds__(256, 3) void fused_attn_st(
    const ushort* __restrict__ Qb,  const ushort* __restrict__ QFb,
    const ushort* __restrict__ Kb,  const ushort* __restrict__ KFb,
    const ushort* __restrict__ Vtb, const ushort* __restrict__ VFtb,
    const float* __restrict__ km_, const float* __restrict__ kv_,
    float* __restrict__ out)
{
    __shared__ ushort SM[20480];                       // 40,960 B -> 3 blocks/CU
    ushort (*K_lds)[264]  = (ushort(*)[264])(SM);          // 32 x 264 (permuted rows)
    ushort (*KF_lds)[264] = (ushort(*)[264])(SM + 8448);
    ushort (*Vt_lds)[40]  = (ushort(*)[40])(SM);           // 256 x 40 (aliases K!)
    ushort (*VFt_lds)[40] = (ushort(*)[40])(SM + 10240);
    float* combuf = (float*)SM;                        // 32 KB, aliases all after loop

    const int tid  = threadIdx.x;
    const int wv   = tid >> 6;
    const int lane = tid & 63;
    const int quad = lane >> 4;
    const int l16  = lane & 15;
    const int qsel = wv & 1;
    const int br   = wv >> 1;          // 0 = channel, 1 = spatial
    const int q0   = blockIdx.x * 32;

    const ushort* qsrc = br ? QFb : Qb;
    bf16x8 aQ[8];
    {
        const ushort* qp = qsrc + (size_t)(q0 + qsel * 16 + l16) * DM + quad * 8;
        #pragma unroll
        for (int s = 0; s < 8; ++s) aQ[s] = *(const bf16x8*)(qp + s * 32);
    }

    float qmv = 0.f, qvv = 0.f;
    if (br) {
        float sum = 0.f, ss = 0.f;
        #pragma unroll
        for (int s = 0; s < 8; ++s)
            #pragma unroll
            for (int j = 0; j < 8; ++j) {
                float v = (float)aQ[s][j];
                sum += v; ss += v * v;
            }
        sum += __shfl_xor(sum, 16, 64); sum += __shfl_xor(sum, 32, 64);
        ss  += __shfl_xor(ss, 16, 64);  ss  += __shfl_xor(ss, 32, 64);
        qmv = sum * (1.f / 256.f);
        qvv = (ss - 256.f * qmv * qmv) * (1.f / 255.f);
    }

    floatx4 acc[16];
    #pragma unroll
    for (int t = 0; t < 16; ++t) acc[t] = (floatx4){0.f, 0.f, 0.f, 0.f};
    float den = 0.f;

    for (int kt = 0; kt < MM; kt += 32) {
        __syncthreads();   // prev tile's PV reads done -> safe to overwrite with K
        // stage K/KF with row permutation: global row r -> LDS row pr
        #pragma unroll
        for (int it = 0; it < 4; ++it) {
            int idx = tid + it * 256;
            int r = idx >> 5, c8 = (idx & 31) * 8;
            int pr = ((r & 4) << 2) | ((r >> 3) << 2) | (r & 3);
            *(uint4*)&K_lds[pr][c8]  = *(const uint4*)(Kb  + (size_t)(kt + r) * DM + c8);
            *(uint4*)&KF_lds[pr][c8] = *(const uint4*)(KFb + (size_t)(kt + r) * DM + c8);
        }
        __syncthreads();

        // ---- S^T scores: A = K rows (2 subtiles), B = Q regs, K=256 ----
        floatx4 S0 = (floatx4){0.f, 0.f, 0.f, 0.f};
        floatx4 S1 = (floatx4){0.f, 0.f, 0.f, 0.f};
        const ushort (*Ksrc)[264] = br ? KF_lds : K_lds;
        #pragma unroll
        for (int s = 0; s < 8; ++s) {
            bf16x8 aK0 = *(const bf16x8*)&Ksrc[l16][s * 32 + quad * 8];
            bf16x8 aK1 = *(const bf16x8*)&Ksrc[16 + l16][s * 32 + quad * 8];
            S0 = __builtin_amdgcn_mfma_f32_16x16x32_bf16(aK0, aQ[s], S0, 0, 0, 0);
            S1 = __builtin_amdgcn_mfma_f32_16x16x32_bf16(aK1, aQ[s], S1, 0, 0, 0);
        }

        // ---- epilogue -> p[8] in regs (A-frag slot j = 4*sub + r, key = 8*quad+j) ----
        float p[8];
        if (!br) {
            #pragma unroll
            for (int r = 0; r < 4; ++r) {
                p[r]     = __expf(S0[r] * 0.0625f);
                p[4 + r] = __expf(S1[r] * 0.0625f);
            }
        } else {
            floatx4 km0 = *(const floatx4*)(km_ + kt + 8 * quad);
            floatx4 km1 = *(const floatx4*)(km_ + kt + 8 * quad + 4);
            floatx4 kv0 = *(const floatx4*)(kv_ + kt + 8 * quad);
            floatx4 kv1 = *(const floatx4*)(kv_ + kt + 8 * quad + 4);
            #pragma unroll
            for (int r = 0; r < 4; ++r) {
                {
                    float mp  = qmv * km0[r];
                    float cov = (S0[r] - 256.f * mp) * (1.f / 255.f);
                    float num = (2.f * mp + 0.01f) * (2.f * cov + 0.03f);
                    float dn  = (qmv * qmv + km0[r] * km0[r] + 0.01f) * (qvv + kv0[r] + 0.03f);
                    p[r] = __expf(num / (dn + 1e-8f));
                }
                {
                    float mp  = qmv * km1[r];
                    float cov = (S1[r] - 256.f * mp) * (1.f / 255.f);
                    float num = (2.f * mp + 0.01f) * (2.f * cov + 0.03f);
                    float dn  = (qmv * qmv + km1[r] * km1[r] + 0.01f) * (qvv + kv1[r] + 0.03f);
                    p[4 + r] = __expf(num / (dn + 1e-8f));
                }
            }
        }
        union { ushort u[8]; bf16x8 v; } ap;
        #pragma unroll
        for (int j = 0; j < 8; ++j) {
            den += p[j];
            ap.u[j] = f2bf(p[j]);
        }

        __syncthreads();   // K/KF reads done -> safe to overwrite with Vt/VFt
        // stage Vt/VFt (256 dims x 32 keys) into the SAME buffer
        #pragma unroll
        for (int it = 0; it < 4; ++it) {
            int idx = tid + it * 256;
            int d = idx >> 2, kc = (idx & 3) * 8;
            *(uint4*)&Vt_lds[d][kc]  = *(const uint4*)(Vtb  + (size_t)d * MM + kt + kc);
            *(uint4*)&VFt_lds[d][kc] = *(const uint4*)(VFtb + (size_t)d * MM + kt + kc);
        }
        __syncthreads();

        // ---- PV: A = P regs, B = Vt[d][quad*8] b128, K=32 ----
        const ushort (*Vsrc)[40] = br ? VFt_lds : Vt_lds;
        #pragma unroll
        for (int t = 0; t < 16; ++t) {
            bf16x8 bV = *(const bf16x8*)&Vsrc[t * 16 + l16][quad * 8];
            acc[t] = __builtin_amdgcn_mfma_f32_16x16x32_bf16(ap.v, bV, acc[t], 0, 0, 0);
        }
    }

    den += __shfl_xor(den, 16, 64);
    den += __shfl_xor(den, 32, 64);
    float rdn[4];
    #pragma unroll
    for (int r = 0; r < 4; ++r)
        rdn[r] = 1.f / __shfl(den, quad * 4 + r, 64);

    __syncthreads();   // last tile's Vt reads done; safe to alias combuf
    if (br) {
        #pragma unroll
        for (int t = 0; t < 16; ++t)
            #pragma unroll
            for (int r = 0; r < 4; ++r)
                combuf[(qsel * 16 + quad * 4 + r) * 256 + t * 16 + l16] = acc[t][r] * rdn[r];
    }
    __syncthreads();
    if (!br) {
        #pragma unroll
        for (int t = 0; t < 16; ++t)
            #pragma unroll
            for (int r = 0; r < 4; ++r) {
                int ql = qsel * 16 + quad * 4 + r;
                out[(size_t)(q0 + ql) * DM + t * 16 + l16] =
                    acc[t][r] * rdn[r] + combuf[ql * 256 + t * 16 + l16];
            }
    }
}

extern "C" void kernel_launch(void* const* d_in, const int* in_sizes, int n_in,
                              void* d_out, int out_size, void* d_ws, size_t ws_size,
                              hipStream_t stream)
{
    const float* x      = (const float*)d_in[0];
    const float* ch_mem = (const float*)d_in[1];
    const float* ch_wq  = (const float*)d_in[2];
    const float* ch_wk  = (const float*)d_in[3];
    const float* ch_wv  = (const float*)d_in[4];
    const float* sp_mem = (const float*)d_in[5];
    const float* sp_wq  = (const float*)d_in[6];
    const float* sp_wk  = (const float*)d_in[7];
    const float* sp_wv  = (const float*)d_in[8];
    float* out = (float*)d_out;

    ushort* Qb   = (ushort*)d_ws;                 // [12544][256]
    ushort* QFb  = Qb   + (size_t)NBQ * DM;
    ushort* Kb   = QFb  + (size_t)NBQ * DM;       // [2048][256]
    ushort* KFb  = Kb   + (size_t)MM * DM;
    ushort* Vtb  = KFb  + (size_t)MM * DM;        // [256][2048] transposed
    ushort* VFtb = Vtb  + (size_t)MM * DM;
    float*  km   = (float*)(VFtb + (size_t)MM * DM);
    float*  kv   = km + MM;

    dim3 blk(256);
    proj_stats<<<dim3(260), blk, 0, stream>>>(
        x, ch_mem, sp_mem, ch_wq, sp_wq, ch_wk, ch_wv, sp_wk, sp_wv,
        Qb, QFb, Kb, KFb, Vtb, VFtb, km, kv);
    fused_attn_st<<<dim3(NBQ / 32), blk, 0, stream>>>(
        Qb, QFb, Kb, KFb, Vtb, VFtb, km, kv, out);
}

// Round 16
// 264.803 us; speedup vs baseline: 1.6569x; 1.6569x over previous
//
#include <hip/hip_runtime.h>

#define NBQ 12544
#define DM  256
#define MM  2048

typedef __attribute__((ext_vector_type(8)))  __bf16 bf16x8;
typedef __attribute__((ext_vector_type(4)))  float  floatx4;

__device__ __forceinline__ ushort f2bf(float x) {
    unsigned u = __float_as_uint(x);
    u += 0x7fffu + ((u >> 16) & 1u);   // RNE
    return (ushort)(u >> 16);
}
__device__ __forceinline__ float bf2f(ushort h) {
    return __uint_as_float(((unsigned)h) << 16);
}

// ---------- projections, weight-pairs folded (r11/r12/r13-proven) ----------
__global__ __launch_bounds__(256) void gemm_proj_all(
    const float* __restrict__ x,      const float* __restrict__ ch_mem,
    const float* __restrict__ ch_wq,  const float* __restrict__ ch_wk,
    const float* __restrict__ ch_wv,  const float* __restrict__ sp_mem,
    const float* __restrict__ sp_wq,  const float* __restrict__ sp_wk,
    const float* __restrict__ sp_wv,
    ushort* __restrict__ Qb,  ushort* __restrict__ QFb,
    ushort* __restrict__ Kb,  ushort* __restrict__ KFb,
    ushort* __restrict__ Vtb, ushort* __restrict__ VFtb)
{
    __shared__ ushort As[64][72];
    __shared__ ushort W1s[64][72];
    __shared__ ushort W2s[64][72];

    int bid = blockIdx.x;
    const float* A; const float* W1; const float* W2;
    ushort* C1; ushort* C2; int nrows, trans2;
    if (bid < 784) {
        A = x; W1 = ch_wq; W2 = sp_wq; C1 = Qb; C2 = QFb; nrows = NBQ; trans2 = 0;
    } else if (bid < 912) {
        A = ch_mem; W1 = ch_wk; W2 = ch_wv; C1 = Kb; C2 = Vtb;
        nrows = MM; trans2 = 1; bid -= 784;
    } else {
        A = sp_mem; W1 = sp_wk; W2 = sp_wv; C1 = KFb; C2 = VFtb;
        nrows = MM; trans2 = 1; bid -= 912;
    }
    const int r0 = (bid >> 2) * 64;
    const int c0 = (bid & 3) * 64;

    const int tid  = threadIdx.x;
    const int wv   = tid >> 6;
    const int lane = tid & 63;
    const int quad = lane >> 4;
    const int l16  = lane & 15;
    const int rw = (wv & 1) * 32;
    const int cw = (wv >> 1) * 32;

    floatx4 acc1[2][2], acc2[2][2];
    #pragma unroll
    for (int i = 0; i < 2; ++i)
        #pragma unroll
        for (int j = 0; j < 2; ++j) {
            acc1[i][j] = (floatx4){0.f, 0.f, 0.f, 0.f};
            acc2[i][j] = (floatx4){0.f, 0.f, 0.f, 0.f};
        }

    for (int d0 = 0; d0 < 256; d0 += 64) {
        __syncthreads();
        #pragma unroll
        for (int it = 0; it < 4; ++it) {
            int idx = tid + it * 256;
            int r = idx >> 4, c4 = (idx & 15) * 4;
            float4 a4 = *(const float4*)(A  + (size_t)(r0 + r) * 256 + d0 + c4);
            float4 w14 = *(const float4*)(W1 + (size_t)(c0 + r) * 256 + d0 + c4);
            float4 w24 = *(const float4*)(W2 + (size_t)(c0 + r) * 256 + d0 + c4);
            ushort4 ab, w1b, w2b;
            ab.x = f2bf(a4.x);  ab.y = f2bf(a4.y);  ab.z = f2bf(a4.z);  ab.w = f2bf(a4.w);
            w1b.x = f2bf(w14.x); w1b.y = f2bf(w14.y); w1b.z = f2bf(w14.z); w1b.w = f2bf(w14.w);
            w2b.x = f2bf(w24.x); w2b.y = f2bf(w24.y); w2b.z = f2bf(w24.z); w2b.w = f2bf(w24.w);
            *(ushort4*)&As[r][c4]  = ab;
            *(ushort4*)&W1s[r][c4] = w1b;
            *(ushort4*)&W2s[r][c4] = w2b;
        }
        __syncthreads();
        #pragma unroll
        for (int kk = 0; kk < 64; kk += 32) {
            bf16x8 aA0 = *(const bf16x8*)&As[rw + l16][kk + quad * 8];
            bf16x8 aA1 = *(const bf16x8*)&As[rw + 16 + l16][kk + quad * 8];
            bf16x8 b10 = *(const bf16x8*)&W1s[cw + l16][kk + quad * 8];
            bf16x8 b11 = *(const bf16x8*)&W1s[cw + 16 + l16][kk + quad * 8];
            bf16x8 b20 = *(const bf16x8*)&W2s[cw + l16][kk + quad * 8];
            bf16x8 b21 = *(const bf16x8*)&W2s[cw + 16 + l16][kk + quad * 8];
            acc1[0][0] = __builtin_amdgcn_mfma_f32_16x16x32_bf16(aA0, b10, acc1[0][0], 0, 0, 0);
            acc1[0][1] = __builtin_amdgcn_mfma_f32_16x16x32_bf16(aA0, b11, acc1[0][1], 0, 0, 0);
            acc1[1][0] = __builtin_amdgcn_mfma_f32_16x16x32_bf16(aA1, b10, acc1[1][0], 0, 0, 0);
            acc1[1][1] = __builtin_amdgcn_mfma_f32_16x16x32_bf16(aA1, b11, acc1[1][1], 0, 0, 0);
            acc2[0][0] = __builtin_amdgcn_mfma_f32_16x16x32_bf16(aA0, b20, acc2[0][0], 0, 0, 0);
            acc2[0][1] = __builtin_amdgcn_mfma_f32_16x16x32_bf16(aA0, b21, acc2[0][1], 0, 0, 0);
            acc2[1][0] = __builtin_amdgcn_mfma_f32_16x16x32_bf16(aA1, b20, acc2[1][0], 0, 0, 0);
            acc2[1][1] = __builtin_amdgcn_mfma_f32_16x16x32_bf16(aA1, b21, acc2[1][1], 0, 0, 0);
        }
    }

    #pragma unroll
    for (int ag = 0; ag < 2; ++ag)
        #pragma unroll
        for (int cg = 0; cg < 2; ++cg)
            #pragma unroll
            for (int i = 0; i < 4; ++i)
                C1[(size_t)(r0 + rw + ag * 16 + quad * 4 + i) * 256
                   + c0 + cw + cg * 16 + l16] = f2bf(acc1[ag][cg][i]);

    if (!trans2) {
        #pragma unroll
        for (int ag = 0; ag < 2; ++ag)
            #pragma unroll
            for (int cg = 0; cg < 2; ++cg)
                #pragma unroll
                for (int i = 0; i < 4; ++i)
                    C2[(size_t)(r0 + rw + ag * 16 + quad * 4 + i) * 256
                       + c0 + cw + cg * 16 + l16] = f2bf(acc2[ag][cg][i]);
    } else {
        __syncthreads();
        #pragma unroll
        for (int ag = 0; ag < 2; ++ag)
            #pragma unroll
            for (int cg = 0; cg < 2; ++cg)
                #pragma unroll
                for (int i = 0; i < 4; ++i)
                    W2s[cw + cg * 16 + l16][rw + ag * 16 + quad * 4 + i] = f2bf(acc2[ag][cg][i]);
        __syncthreads();
        const int col = tid >> 2;
        const int seg = (tid & 3) * 16;
        #pragma unroll
        for (int j = 0; j < 2; ++j)
            *(uint4*)(C2 + (size_t)(c0 + col) * nrows + r0 + seg + j * 8) =
                *(const uint4*)&W2s[col][seg + j * 8];
    }
}

// ---------------- KF row stats only (Q stats inline in fused) ----------------
__global__ __launch_bounds__(256) void row_stats_kf(
    const ushort* __restrict__ KFb, float* __restrict__ km, float* __restrict__ kv)
{
    const int row  = blockIdx.x * 4 + (threadIdx.x >> 6);
    const int lane = threadIdx.x & 63;
    ushort4 u = *(const ushort4*)(KFb + (size_t)row * 256 + lane * 4);
    float a = bf2f(u.x), b = bf2f(u.y), c = bf2f(u.z), d = bf2f(u.w);
    float s  = a + b + c + d;
    float ss = a * a + b * b + c * c + d * d;
    #pragma unroll
    for (int off = 32; off > 0; off >>= 1) {
        s  += __shfl_down(s, off);
        ss += __shfl_down(ss, off);
    }
    if (lane == 0) {
        float m = s * (1.f / 256.f);
        km[row] = m;
        kv[row] = (ss - 256.f * m * m) * (1.f / 255.f);
    }
}

// ---------------- fused dual attention: S^T scores, P in registers (r13 best) -------
// Block: 32 queries, 4 waves. Wave roles: qsel = wv&1, branch = wv>>1 (0=ch, 1=sp).
// Scores TRANSPOSED (A=K, B=Q). K LDS rows permuted so the epilogue's 8 p-values per
// lane are exactly PV A-frag slots -> no P LDS round-trip. K+V co-staged at tile top
// (phase-split staging is a proven 2x regression — r7/r15). 2 barriers/tile.
__global__ __launch_bounds__(256, 2) void fused_attn_st(
    const ushort* __restrict__ Qb,  const ushort* __restrict__ QFb,
    const ushort* __restrict__ Kb,  const ushort* __restrict__ KFb,
    const ushort* __restrict__ Vtb, const ushort* __restrict__ VFtb,
    const float* __restrict__ km_, const float* __restrict__ kv_,
    float* __restrict__ out)
{
    __shared__ ushort SM[37376];                       // 74752 B -> 2 blocks/CU
    ushort (*K_lds)[264]  = (ushort(*)[264])(SM);          // 32 x 264 (permuted rows)
    ushort (*KF_lds)[264] = (ushort(*)[264])(SM + 8448);
    ushort (*Vt_lds)[40]  = (ushort(*)[40])(SM + 16896);   // 256 x 40
    ushort (*VFt_lds)[40] = (ushort(*)[40])(SM + 27136);
    float* combuf = (float*)(SM + 16896);              // 32 KB, aliases Vt after loop

    const int tid  = threadIdx.x;
    const int wv   = tid >> 6;
    const int lane = tid & 63;
    const int quad = lane >> 4;
    const int l16  = lane & 15;
    const int qsel = wv & 1;
    const int br   = wv >> 1;          // 0 = channel, 1 = spatial
    const int q0   = blockIdx.x * 32;

    const ushort* qsrc = br ? QFb : Qb;
    bf16x8 aQ[8];
    {
        const ushort* qp = qsrc + (size_t)(q0 + qsel * 16 + l16) * DM + quad * 8;
        #pragma unroll
        for (int s = 0; s < 8; ++s) aQ[s] = *(const bf16x8*)(qp + s * 32);
    }

    float qmv = 0.f, qvv = 0.f;
    if (br) {
        float sum = 0.f, ss = 0.f;
        #pragma unroll
        for (int s = 0; s < 8; ++s)
            #pragma unroll
            for (int j = 0; j < 8; ++j) {
                float v = (float)aQ[s][j];
                sum += v; ss += v * v;
            }
        sum += __shfl_xor(sum, 16, 64); sum += __shfl_xor(sum, 32, 64);
        ss  += __shfl_xor(ss, 16, 64);  ss  += __shfl_xor(ss, 32, 64);
        qmv = sum * (1.f / 256.f);
        qvv = (ss - 256.f * qmv * qmv) * (1.f / 255.f);
    }

    floatx4 acc[16];
    #pragma unroll
    for (int t = 0; t < 16; ++t) acc[t] = (floatx4){0.f, 0.f, 0.f, 0.f};
    float den = 0.f;

    for (int kt = 0; kt < MM; kt += 32) {
        __syncthreads();
        #pragma unroll
        for (int it = 0; it < 4; ++it) {
            int idx = tid + it * 256;
            int r = idx >> 5, c8 = (idx & 31) * 8;
            int pr = ((r & 4) << 2) | ((r >> 3) << 2) | (r & 3);
            *(uint4*)&K_lds[pr][c8]  = *(const uint4*)(Kb  + (size_t)(kt + r) * DM + c8);
            *(uint4*)&KF_lds[pr][c8] = *(const uint4*)(KFb + (size_t)(kt + r) * DM + c8);
        }
        #pragma unroll
        for (int it = 0; it < 4; ++it) {
            int idx = tid + it * 256;
            int d = idx >> 2, kc = (idx & 3) * 8;
            *(uint4*)&Vt_lds[d][kc]  = *(const uint4*)(Vtb  + (size_t)d * MM + kt + kc);
            *(uint4*)&VFt_lds[d][kc] = *(const uint4*)(VFtb + (size_t)d * MM + kt + kc);
        }
        __syncthreads();

        floatx4 S0 = (floatx4){0.f, 0.f, 0.f, 0.f};
        floatx4 S1 = (floatx4){0.f, 0.f, 0.f, 0.f};
        const ushort (*Ksrc)[264] = br ? KF_lds : K_lds;
        #pragma unroll
        for (int s = 0; s < 8; ++s) {
            bf16x8 aK0 = *(const bf16x8*)&Ksrc[l16][s * 32 + quad * 8];
            bf16x8 aK1 = *(const bf16x8*)&Ksrc[16 + l16][s * 32 + quad * 8];
            S0 = __builtin_amdgcn_mfma_f32_16x16x32_bf16(aK0, aQ[s], S0, 0, 0, 0);
            S1 = __builtin_amdgcn_mfma_f32_16x16x32_bf16(aK1, aQ[s], S1, 0, 0, 0);
        }

        float p[8];
        if (!br) {
            #pragma unroll
            for (int r = 0; r < 4; ++r) {
                p[r]     = __expf(S0[r] * 0.0625f);
                p[4 + r] = __expf(S1[r] * 0.0625f);
            }
        } else {
            floatx4 km0 = *(const floatx4*)(km_ + kt + 8 * quad);
            floatx4 km1 = *(const floatx4*)(km_ + kt + 8 * quad + 4);
            floatx4 kv0 = *(const floatx4*)(kv_ + kt + 8 * quad);
            floatx4 kv1 = *(const floatx4*)(kv_ + kt + 8 * quad + 4);
            #pragma unroll
            for (int r = 0; r < 4; ++r) {
                {
                    float mp  = qmv * km0[r];
                    float cov = (S0[r] - 256.f * mp) * (1.f / 255.f);
                    float num = (2.f * mp + 0.01f) * (2.f * cov + 0.03f);
                    float dn  = (qmv * qmv + km0[r] * km0[r] + 0.01f) * (qvv + kv0[r] + 0.03f);
                    p[r] = __expf(num / (dn + 1e-8f));
                }
                {
                    float mp  = qmv * km1[r];
                    float cov = (S1[r] - 256.f * mp) * (1.f / 255.f);
                    float num = (2.f * mp + 0.01f) * (2.f * cov + 0.03f);
                    float dn  = (qmv * qmv + km1[r] * km1[r] + 0.01f) * (qvv + kv1[r] + 0.03f);
                    p[4 + r] = __expf(num / (dn + 1e-8f));
                }
            }
        }
        union { ushort u[8]; bf16x8 v; } ap;
        #pragma unroll
        for (int j = 0; j < 8; ++j) {
            den += p[j];
            ap.u[j] = f2bf(p[j]);
        }

        const ushort (*Vsrc)[40] = br ? VFt_lds : Vt_lds;
        #pragma unroll
        for (int t = 0; t < 16; ++t) {
            bf16x8 bV = *(const bf16x8*)&Vsrc[t * 16 + l16][quad * 8];
            acc[t] = __builtin_amdgcn_mfma_f32_16x16x32_bf16(ap.v, bV, acc[t], 0, 0, 0);
        }
    }

    den += __shfl_xor(den, 16, 64);
    den += __shfl_xor(den, 32, 64);
    float rdn[4];
    #pragma unroll
    for (int r = 0; r < 4; ++r)
        rdn[r] = 1.f / __shfl(den, quad * 4 + r, 64);

    __syncthreads();
    if (br) {
        #pragma unroll
        for (int t = 0; t < 16; ++t)
            #pragma unroll
            for (int r = 0; r < 4; ++r)
                combuf[(qsel * 16 + quad * 4 + r) * 256 + t * 16 + l16] = acc[t][r] * rdn[r];
    }
    __syncthreads();
    if (!br) {
        #pragma unroll
        for (int t = 0; t < 16; ++t)
            #pragma unroll
            for (int r = 0; r < 4; ++r) {
                int ql = qsel * 16 + quad * 4 + r;
                out[(size_t)(q0 + ql) * DM + t * 16 + l16] =
                    acc[t][r] * rdn[r] + combuf[ql * 256 + t * 16 + l16];
            }
    }
}

extern "C" void kernel_launch(void* const* d_in, const int* in_sizes, int n_in,
                              void* d_out, int out_size, void* d_ws, size_t ws_size,
                              hipStream_t stream)
{
    const float* x      = (const float*)d_in[0];
    const float* ch_mem = (const float*)d_in[1];
    const float* ch_wq  = (const float*)d_in[2];
    const float* ch_wk  = (const float*)d_in[3];
    const float* ch_wv  = (const float*)d_in[4];
    const float* sp_mem = (const float*)d_in[5];
    const float* sp_wq  = (const float*)d_in[6];
    const float* sp_wk  = (const float*)d_in[7];
    const float* sp_wv  = (const float*)d_in[8];
    float* out = (float*)d_out;

    ushort* Qb   = (ushort*)d_ws;                 // [12544][256]
    ushort* QFb  = Qb   + (size_t)NBQ * DM;
    ushort* Kb   = QFb  + (size_t)NBQ * DM;       // [2048][256]
    ushort* KFb  = Kb   + (size_t)MM * DM;
    ushort* Vtb  = KFb  + (size_t)MM * DM;        // [256][2048] transposed
    ushort* VFtb = Vtb  + (size_t)MM * DM;
    float*  km   = (float*)(VFtb + (size_t)MM * DM);
    float*  kv   = km + MM;

    dim3 blk(256);
    gemm_proj_all<<<dim3(1040), blk, 0, stream>>>(
        x, ch_mem, ch_wq, ch_wk, ch_wv, sp_mem, sp_wq, sp_wk, sp_wv,
        Qb, QFb, Kb, KFb, Vtb, VFtb);
    row_stats_kf<<<dim3(MM / 4), blk, 0, stream>>>(KFb, km, kv);
    fused_attn_st<<<dim3(NBQ / 32), blk, 0, stream>>>(
        Qb, QFb, Kb, KFb, Vtb, VFtb, km, kv, out);
}